// Round 19
// baseline (34.673 us; speedup 1.0000x reference)
//
#include <hip/hip_runtime.h>
#include <math.h>

#define KK 20
#define NPTS 8192
#define NQB 4               // queries per block
#define QPL 4               // queries per lane (= NQB)
#define NCH 256             // chunks per query (32 pts: 4 windows x 8 consecutive)
#define THREADS 256
#define WIN 2048
#define NWIN 4
#define JPW 8               // consecutive points per chunk per window
#define CAP 64              // hit buffer capacity per query
#define MAXC 64             // candidate-chunk list capacity per query
#define MARGIN 4e-3f        // >> 2*max|d_fast - d_exact|

// Exact (non-contracted) IEEE ops matching the NumPy reference bit-for-bit.
// np.sum (pairwise, n<8) accumulates ascending: (x^2 + y^2) + z^2.
__device__ __forceinline__ float norm3(float x, float y, float z) {
    return __fadd_rn(__fadd_rn(__fmul_rn(x, x), __fmul_rn(y, y)), __fmul_rn(z, z));
}

// np.einsum (optimize=False) remainder falls through DESCENDING for count=3:
// ((z*z') + y*y') + x*x'.  dist = ((-2*dot) + n_src) + n_dst.
__device__ __forceinline__ float dist_exact(float px, float py, float pz, float pw,
                                            float qx, float qy, float qz, float qn) {
    const float dot = __fadd_rn(
        __fadd_rn(__fmul_rn(pz, qz), __fmul_rn(py, qy)), __fmul_rn(px, qx));
    return __fadd_rn(__fadd_rn(__fmul_rn(dot, -2.0f), pw), qn);
}

extern "C" __global__ __launch_bounds__(THREADS, 8)
void knn_kernel(const float* __restrict__ verts, int* __restrict__ out)
{
    // Static LDS 7168 B. Grid 2048 = 8 blocks/CU = 32 waves/CU (HW max).
    __shared__ float  vdump[NQB][NCH];          // 4096 B (row per query)
    __shared__ float  hbd[NQB][CAP];            // 1024 B
    __shared__ int    hbi[NQB][CAP];            // 1024 B
    __shared__ int    cand[NQB][MAXC];          // 1024 B

    const int t    = threadIdx.x;
    const int lane = t & 63;
    const int wv   = t >> 6;          // wave 0..3 (= its query)
    const int c    = t;               // chunk 0..255 (one per thread)
    const int qbase = blockIdx.x * NQB;

    // Register tile: all 4 block queries per lane. Fast path: folded -2*q
    // coords, qn omitted inside the min (constant per query, re-added once).
    float qx2[QPL], qy2[QPL], qz2[QPL], qn[QPL];
#pragma unroll
    for (int i = 0; i < QPL; ++i) {
        const float x = verts[(qbase + i) * 3 + 0];
        const float y = verts[(qbase + i) * 3 + 1];
        const float z = verts[(qbase + i) * 3 + 2];
        qn[i] = norm3(x, y, z);
        qx2[i] = -2.0f * x; qy2[i] = -2.0f * y; qz2[i] = -2.0f * z;
    }

    // ---------------- PASS 1: per-(chunk,query) MIN, straight from global ---
    // Chunk c = { w*WIN + c*JPW + j : w<4, j<8 }; per window two batches of
    // 4 points (3 aligned float4 each) keep the live set small (<=12 regs).
    // NO barriers, NO LDS in this phase: waves fully decoupled.
    float mn[QPL];
#pragma unroll
    for (int i = 0; i < QPL; ++i) mn[i] = INFINITY;

    auto pair4 = [&](float px, float py, float pz) {
        const float pw = norm3(px, py, pz);
#pragma unroll
        for (int i = 0; i < QPL; ++i) {
            const float d = __builtin_fmaf(px, qx2[i],
                            __builtin_fmaf(py, qy2[i],
                            __builtin_fmaf(pz, qz2[i], pw)));
            mn[i] = fminf(mn[i], d);
        }
    };

#pragma unroll
    for (int w = 0; w < NWIN; ++w) {
        const float4* vp = (const float4*)(verts + (w * WIN + c * JPW) * 3);
        {   // points 0..3
            const float4 A = vp[0], B = vp[1], C = vp[2];
            pair4(A.x, A.y, A.z); pair4(A.w, B.x, B.y);
            pair4(B.z, B.w, C.x); pair4(C.y, C.z, C.w);
        }
        {   // points 4..7
            const float4 A = vp[3], B = vp[4], C = vp[5];
            pair4(A.x, A.y, A.z); pair4(A.w, B.x, B.y);
            pair4(B.z, B.w, C.x); pair4(C.y, C.z, C.w);
        }
    }

    // Re-add qn so vdump holds true fast distances (row per query).
#pragma unroll
    for (int i = 0; i < QPL; ++i) {
        mn[i] += qn[i];
        vdump[i][c] = mn[i];
    }
    __syncthreads();
    // -------- From here on, EVERYTHING is wave-local (no barriers/atomics). --
    // Wave wv owns query wv.

    const int qq = wv;
    float T; int nc;
    {
        // One aligned b128 per lane: elements lane*4 .. lane*4+3 of query row.
        const float4 sv = *(const float4*)&vdump[qq][lane * 4];

        // ---- T' = 20th smallest of 256 chunk-minima (bitonic, 4 regs/lane) --
        float r0 = sv.x, r1 = sv.y, r2 = sv.z, r3 = sv.w;
        { const float lo = fminf(r0, r1), hi = fmaxf(r0, r1); r0 = lo; r1 = hi; }
        { const float lo = fminf(r2, r3), hi = fmaxf(r2, r3); r2 = hi; r3 = lo; }
#pragma unroll
        for (int k = 4; k <= 256; k <<= 1) {
            const bool asc = (((lane << 2) & k) == 0);
#pragma unroll
            for (int j = k >> 1; j >= 4; j >>= 1) {
                const int lj = j >> 2;
                const bool lower = ((lane & lj) == 0);
                const bool keepmin = (lower == asc);
                const float o0 = __shfl_xor(r0, lj), o1 = __shfl_xor(r1, lj);
                const float o2 = __shfl_xor(r2, lj), o3 = __shfl_xor(r3, lj);
                r0 = keepmin ? fminf(r0, o0) : fmaxf(r0, o0);
                r1 = keepmin ? fminf(r1, o1) : fmaxf(r1, o1);
                r2 = keepmin ? fminf(r2, o2) : fmaxf(r2, o2);
                r3 = keepmin ? fminf(r3, o3) : fmaxf(r3, o3);
            }
            {   // j = 2
                const float lo0 = fminf(r0, r2), hi0 = fmaxf(r0, r2);
                const float lo1 = fminf(r1, r3), hi1 = fmaxf(r1, r3);
                r0 = asc ? lo0 : hi0; r2 = asc ? hi0 : lo0;
                r1 = asc ? lo1 : hi1; r3 = asc ? hi1 : lo1;
            }
            {   // j = 1
                const float lo0 = fminf(r0, r1), hi0 = fmaxf(r0, r1);
                const float lo1 = fminf(r2, r3), hi1 = fmaxf(r2, r3);
                r0 = asc ? lo0 : hi0; r1 = asc ? hi0 : lo0;
                r2 = asc ? lo1 : hi1; r3 = asc ? hi1 : lo1;
            }
        }
        T = __shfl(r3, 4) + MARGIN;             // element 19 = lane 4, reg 3

        // ---- Candidate chunks via ballot compaction (no atomics) -----------
        const unsigned long long b0 = __ballot(sv.x <= T);
        const unsigned long long b1 = __ballot(sv.y <= T);
        const unsigned long long b2 = __ballot(sv.z <= T);
        const unsigned long long b3 = __ballot(sv.w <= T);
        const int c0 = __popcll(b0), c1 = __popcll(b1), c2 = __popcll(b2);
        const unsigned long long below = (1ULL << lane) - 1;
        const int k0 = __popcll(b0 & below);
        const int k1 = c0 + __popcll(b1 & below);
        const int k2 = c0 + c1 + __popcll(b2 & below);
        const int k3 = c0 + c1 + c2 + __popcll(b3 & below);
        if ((sv.x <= T) && k0 < MAXC) cand[qq][k0] = lane * 4 + 0;
        if ((sv.y <= T) && k1 < MAXC) cand[qq][k1] = lane * 4 + 1;
        if ((sv.z <= T) && k2 < MAXC) cand[qq][k2] = lane * 4 + 2;
        if ((sv.w <= T) && k3 < MAXC) cand[qq][k3] = lane * 4 + 3;
        nc = min(c0 + c1 + c2 + __popcll(b3), MAXC);
    }

    // ------- PASS 2 (sparse): whole wave on query wv, 2 cands/u, 4-deep -----
    // lane>>5 picks candidate e0+2u+(lane>>5); p = lane&31 maps to point
    // n = (p>>3)*WIN + cc*JPW + (p&7)  (the chunk's true point set).
    int hc = 0;                                 // hit count (wave-uniform)
    {
        const int qg2 = qbase + qq;
        const float qxe = verts[qg2 * 3 + 0];
        const float qye = verts[qg2 * 3 + 1];
        const float qze = verts[qg2 * 3 + 2];
        const float qne = norm3(qxe, qye, qze);
        const int half = lane >> 5;
        const int p = lane & 31;
        const int nfix = (p >> 3) * WIN + (p & 7);
        for (int e0 = 0; e0 < nc; e0 += 8) {    // wave-uniform, 8 cands/group
            float PX[4], PY[4], PZ[4]; int NN[4];
#pragma unroll
            for (int u = 0; u < 4; ++u) {       // 12 independent loads in flight
                const int e = e0 + 2 * u + half;
                const int cc = cand[qq][e < nc ? e : 0];
                const int n = nfix + cc * JPW;
                NN[u] = n;
                PX[u] = verts[n * 3 + 0];
                PY[u] = verts[n * 3 + 1];
                PZ[u] = verts[n * 3 + 2];
            }
#pragma unroll
            for (int u = 0; u < 4; ++u) {
                const float pw = norm3(PX[u], PY[u], PZ[u]);
                const float d = dist_exact(PX[u], PY[u], PZ[u], pw,
                                           qxe, qye, qze, qne);
                const bool pred = ((e0 + 2 * u + half) < nc) && (d <= T);
                // Ballot-compacted hit append (no atomics), full-wave rank.
                const unsigned long long bal = __ballot(pred);
                const int rank = __popcll(bal & ((1ULL << lane) - 1));
                if (pred) {
                    const int slot = hc + rank;
                    if (slot < CAP) { hbd[qq][slot] = d; hbi[qq][slot] = NN[u]; }
                }
                hc += __popcll(bal);
            }
        }
    }

    // ------- Final: exact stable top-20 via u64 bitonic (query wv) ----------
    {
        const int kc = min(hc, CAP);            // kc >= 20 guaranteed
        unsigned long long key = ~0ULL;
        if (lane < kc) {
            const float d = hbd[qq][lane];
            unsigned u = __float_as_uint(d);
            u ^= ((unsigned)((int)u >> 31)) | 0x80000000u;   // order-preserving map
            key = ((unsigned long long)u << 32) | (unsigned)hbi[qq][lane];
        }
#pragma unroll
        for (int k = 2; k <= 64; k <<= 1) {
#pragma unroll
            for (int j = k >> 1; j >= 1; j >>= 1) {
                const unsigned long long o = __shfl_xor(key, j);
                const bool asc = ((lane & k) == 0);
                const bool lower = ((lane & j) == 0);
                const bool keepmin = (lower == asc);
                const bool lt = key < o;
                key = (keepmin == lt) ? key : o;
            }
        }
        if (lane < KK)
            out[(qbase + qq) * KK + lane] =
                (int)(unsigned)(key & 0xffffffffULL);
    }
}

extern "C" void kernel_launch(void* const* d_in, const int* in_sizes, int n_in,
                              void* d_out, int out_size, void* d_ws, size_t ws_size,
                              hipStream_t stream) {
    // d_in[0] = feats (unused). d_in[1] = vertices [4,8192,3] f32; batch 0 only.
    const float* verts = (const float*)d_in[1];
    int* out = (int*)d_out;
    knn_kernel<<<dim3(NPTS / NQB), dim3(THREADS), 0, stream>>>(verts, out);
}

// Round 20
// 27.498 us; speedup vs baseline: 1.2609x; 1.2609x over previous
//
#include <hip/hip_runtime.h>
#include <math.h>

#define KK 20
#define NPTS 8192
#define NQB 8               // queries per block
#define QPL 8               // queries per lane (pass 1)
#define NCH 256             // chunks per query (32 pts: 4 windows x 8 consecutive)
#define THREADS 256
#define WIN 2048
#define NWIN 4
#define JPW 8               // consecutive points per chunk per window
#define CAP 64              // hit buffer capacity per query
#define MAXC 64             // candidate-chunk list capacity per query
#define MARGIN 4e-3f        // >> 2*max|d_fast - d_exact|

// Exact (non-contracted) IEEE ops matching the NumPy reference bit-for-bit.
// np.sum (pairwise, n<8) accumulates ascending: (x^2 + y^2) + z^2.
__device__ __forceinline__ float norm3(float x, float y, float z) {
    return __fadd_rn(__fadd_rn(__fmul_rn(x, x), __fmul_rn(y, y)), __fmul_rn(z, z));
}

// np.einsum (optimize=False) remainder falls through DESCENDING for count=3:
// ((z*z') + y*y') + x*x'.  dist = ((-2*dot) + n_src) + n_dst.
__device__ __forceinline__ float dist_exact(float px, float py, float pz, float pw,
                                            float qx, float qy, float qz, float qn) {
    const float dot = __fadd_rn(
        __fadd_rn(__fmul_rn(pz, qz), __fmul_rn(py, qy)), __fmul_rn(px, qx));
    return __fadd_rn(__fadd_rn(__fmul_rn(dot, -2.0f), pw), qn);
}

// Order-preserving float -> u32 map (strictly monotone for all finite floats).
__device__ __forceinline__ unsigned omap(float f) {
    const unsigned u = __float_as_uint(f);
    return u ^ (((unsigned)((int)u >> 31)) | 0x80000000u);
}

extern "C" __global__ __launch_bounds__(THREADS, 4)
void knn_kernel(const float* __restrict__ verts, int* __restrict__ out)
{
    // Static LDS 14336 B. Grid 1024 = 4 blocks/CU.
    __shared__ float vdump[NQB][NCH];                   // 8192 B (row per query)
    __shared__ unsigned long long hbk[NQB][CAP];        // 4096 B (packed hit keys)
    __shared__ int cand[NQB][MAXC];                     // 2048 B

    const int t    = threadIdx.x;
    const int lane = t & 63;
    const int wv   = t >> 6;          // wave 0..3
    const int c    = t;               // chunk 0..255 (one per thread)
    const int qbase = blockIdx.x * NQB;

    // Register tile: all 8 block queries per lane. Fast path: folded -2*q
    // coords, qn omitted inside the min (constant per query, re-added once).
    float qx2[QPL], qy2[QPL], qz2[QPL], qn[QPL];
#pragma unroll
    for (int i = 0; i < QPL; ++i) {
        const float x = verts[(qbase + i) * 3 + 0];
        const float y = verts[(qbase + i) * 3 + 1];
        const float z = verts[(qbase + i) * 3 + 2];
        qn[i] = norm3(x, y, z);
        qx2[i] = -2.0f * x; qy2[i] = -2.0f * y; qz2[i] = -2.0f * z;
    }

    // ---------------- PASS 1: per-(chunk,query) MIN, straight from global ---
    // Chunk c's point set: { w*WIN + c*JPW + j : w<4, j<8 }. Per window the
    // chunk is 24 consecutive floats = 6 aligned float4 (96B-aligned base).
    // NO barriers, NO LDS in this phase: waves fully decoupled.
    float mn[QPL];
#pragma unroll
    for (int i = 0; i < QPL; ++i) mn[i] = INFINITY;

    auto pair8 = [&](float px, float py, float pz) {
        const float pw = norm3(px, py, pz);
#pragma unroll
        for (int i = 0; i < QPL; ++i) {
            const float d = __builtin_fmaf(px, qx2[i],
                            __builtin_fmaf(py, qy2[i],
                            __builtin_fmaf(pz, qz2[i], pw)));
            mn[i] = fminf(mn[i], d);
        }
    };

#pragma unroll
    for (int w = 0; w < NWIN; ++w) {
        const float4* vp = (const float4*)(verts + (w * WIN + c * JPW) * 3);
        const float4 A = vp[0], B = vp[1], C = vp[2];
        const float4 D = vp[3], E = vp[4], F = vp[5];
        pair8(A.x, A.y, A.z); pair8(A.w, B.x, B.y);
        pair8(B.z, B.w, C.x); pair8(C.y, C.z, C.w);
        pair8(D.x, D.y, D.z); pair8(D.w, E.x, E.y);
        pair8(E.z, E.w, F.x); pair8(F.y, F.z, F.w);
    }

    // Re-add qn so vdump holds true fast distances (row per query).
#pragma unroll
    for (int i = 0; i < QPL; ++i) {
        mn[i] += qn[i];
        vdump[i][c] = mn[i];
    }
    __syncthreads();
    // -------- From here on, EVERYTHING is wave-local (no barriers/atomics). --
    // Wave wv owns queries {2wv, 2wv+1}.

    float Tr[2]; int ncr[2];
#pragma unroll
    for (int r = 0; r < 2; ++r) {
        const int qq = wv * 2 + r;
        // One aligned b128 per lane: elements lane*4 .. lane*4+3 of query row.
        const float4 sv = *(const float4*)&vdump[qq][lane * 4];

        // ---- T' = 20th smallest of 256 chunk-minima via bitwise binary
        // search on order-mapped u32 (ballot+popcount; no LDS-pipe shfl chain).
        const unsigned u0 = omap(sv.x), u1 = omap(sv.y);
        const unsigned u2 = omap(sv.z), u3 = omap(sv.w);
        unsigned A = 0;
#pragma unroll
        for (int b = 31; b >= 0; --b) {
            const unsigned cv = A | (1u << b);
            const int cnt = __popcll(__ballot(u0 < cv)) + __popcll(__ballot(u1 < cv))
                          + __popcll(__ballot(u2 < cv)) + __popcll(__ballot(u3 < cv));
            if (cnt <= KK - 1) A = cv;   // max A with count(< A) <= 19 => 20th smallest
        }
        const float Tsel = (A >> 31) ? __uint_as_float(A ^ 0x80000000u)
                                     : __uint_as_float(~A);
        const float T = Tsel + MARGIN;
        Tr[r] = T;

        // ---- Candidate chunks via ballot compaction (no atomics) -----------
        const unsigned long long b0 = __ballot(sv.x <= T);
        const unsigned long long b1 = __ballot(sv.y <= T);
        const unsigned long long b2 = __ballot(sv.z <= T);
        const unsigned long long b3 = __ballot(sv.w <= T);
        const int c0 = __popcll(b0), c1 = __popcll(b1), c2 = __popcll(b2);
        const unsigned long long below = (1ULL << lane) - 1;
        const int k0 = __popcll(b0 & below);
        const int k1 = c0 + __popcll(b1 & below);
        const int k2 = c0 + c1 + __popcll(b2 & below);
        const int k3 = c0 + c1 + c2 + __popcll(b3 & below);
        if ((sv.x <= T) && k0 < MAXC) cand[qq][k0] = lane * 4 + 0;
        if ((sv.y <= T) && k1 < MAXC) cand[qq][k1] = lane * 4 + 1;
        if ((sv.z <= T) && k2 < MAXC) cand[qq][k2] = lane * 4 + 2;
        if ((sv.w <= T) && k3 < MAXC) cand[qq][k3] = lane * 4 + 3;
        ncr[r] = min(c0 + c1 + c2 + __popcll(b3), MAXC);
    }

    // ------- PASS 2 (sparse, fused 2 queries/wave, 4-deep pipeline) ---------
    // Half-wave = one query: lanes 0-31 -> q=2wv, lanes 32-63 -> q=2wv+1.
    // Point p = lane&31 of chunk cc: n = (p>>3)*WIN + cc*JPW + (p&7).
    // Hits stored as packed u64 keys (order-mapped dist << 32 | idx); slot
    // order is irrelevant (rank phase sorts globally by key).
    int hc0 = 0, hc1 = 0;                       // per-query hit counts (uniform)
    {
        const int qq = wv * 2 + (lane >> 5);
        const int qg2 = qbase + qq;
        const float qxe = verts[qg2 * 3 + 0];
        const float qye = verts[qg2 * 3 + 1];
        const float qze = verts[qg2 * 3 + 2];
        const float qne = norm3(qxe, qye, qze);
        const float T = (lane < 32) ? Tr[0] : Tr[1];
        const int ncq = (lane < 32) ? ncr[0] : ncr[1];
        const int ncm = max(ncr[0], ncr[1]);
        const int p = lane & 31;
        const int nfix = (p >> 3) * WIN + (p & 7);
        for (int e0 = 0; e0 < ncm; e0 += 4) {   // wave-uniform groups of 4
            float PX[4], PY[4], PZ[4]; int NN[4];
#pragma unroll
            for (int u = 0; u < 4; ++u) {       // 12 independent loads in flight
                const int e = e0 + u;
                const int cc = cand[qq][e < ncq ? e : 0];
                const int n = nfix + cc * JPW;
                NN[u] = n;
                PX[u] = verts[n * 3 + 0];
                PY[u] = verts[n * 3 + 1];
                PZ[u] = verts[n * 3 + 2];
            }
#pragma unroll
            for (int u = 0; u < 4; ++u) {
                const float pw = norm3(PX[u], PY[u], PZ[u]);
                const float d = dist_exact(PX[u], PY[u], PZ[u], pw,
                                           qxe, qye, qze, qne);
                const bool pred = ((e0 + u) < ncq) && (d <= T);
                // Ballot-compacted hit append (no atomics).
                const unsigned long long bal = __ballot(pred);
                const int lc = __popcll(bal & 0xFFFFFFFFULL);
                const int hcv = __popcll(bal >> 32);
                const int base = (lane < 32) ? hc0 : hc1;
                const unsigned long long blw = bal & ((1ULL << lane) - 1);
                const int rank = (lane < 32) ? __popcll(blw)
                                             : __popcll(blw >> 32);
                if (pred) {
                    const int slot = base + rank;
                    if (slot < CAP)
                        hbk[qq][slot] = ((unsigned long long)omap(d) << 32)
                                      | (unsigned)NN[u];
                }
                hc0 += lc; hc1 += hcv;
            }
        }
    }

    // ------- Final: stable top-20 via rank selection (no sort chain) --------
    // rank = #{keys < mine} over the kc hits; unique keys => exact stable
    // ascending (d, idx) order; lanes with rank < 20 scatter their index.
#pragma unroll
    for (int r = 0; r < 2; ++r) {
        const int qq = wv * 2 + r;
        const int kc = min((r == 0) ? hc0 : hc1, CAP);   // kc >= 20 guaranteed
        const unsigned long long mykey =
            (lane < kc) ? hbk[qq][lane] : ~0ULL;
        int rank = 0;
        for (int e = 0; e < kc; ++e)            // broadcast LDS reads, pipelined
            rank += (hbk[qq][e] < mykey) ? 1 : 0;
        if (lane < kc && rank < KK)
            out[(qbase + qq) * KK + rank] =
                (int)(unsigned)(mykey & 0xffffffffULL);
    }
}

extern "C" void kernel_launch(void* const* d_in, const int* in_sizes, int n_in,
                              void* d_out, int out_size, void* d_ws, size_t ws_size,
                              hipStream_t stream) {
    // d_in[0] = feats (unused). d_in[1] = vertices [4,8192,3] f32; batch 0 only.
    const float* verts = (const float*)d_in[1];
    int* out = (int*)d_out;
    knn_kernel<<<dim3(NPTS / NQB), dim3(THREADS), 0, stream>>>(verts, out);
}

// Round 21
// 27.429 us; speedup vs baseline: 1.2641x; 1.0025x over previous
//
#include <hip/hip_runtime.h>
#include <math.h>

#define KK 20
#define NPTS 8192
#define NQB 8               // queries per block
#define QPL 8               // queries per lane (pass 1)
#define NCH 256             // chunks per query (32 pts: 4 windows x 8 consecutive)
#define THREADS 256
#define WIN 2048
#define NWIN 4
#define JPW 8               // consecutive points per chunk per window
#define CAP 64              // hit buffer capacity per query
#define MAXC 64             // candidate-chunk list capacity per query
#define MARGIN 4e-3f        // >> 2*max|d_fast - d_exact|
#define PD 6                // pass-2 pipeline depth

// Exact (non-contracted) IEEE ops matching the NumPy reference bit-for-bit.
// np.sum (pairwise, n<8) accumulates ascending: (x^2 + y^2) + z^2.
__device__ __forceinline__ float norm3(float x, float y, float z) {
    return __fadd_rn(__fadd_rn(__fmul_rn(x, x), __fmul_rn(y, y)), __fmul_rn(z, z));
}

// np.einsum (optimize=False) remainder falls through DESCENDING for count=3:
// ((z*z') + y*y') + x*x'.  dist = ((-2*dot) + n_src) + n_dst.
__device__ __forceinline__ float dist_exact(float px, float py, float pz, float pw,
                                            float qx, float qy, float qz, float qn) {
    const float dot = __fadd_rn(
        __fadd_rn(__fmul_rn(pz, qz), __fmul_rn(py, qy)), __fmul_rn(px, qx));
    return __fadd_rn(__fadd_rn(__fmul_rn(dot, -2.0f), pw), qn);
}

// Order-preserving float -> u32 map (strictly monotone for all finite floats).
__device__ __forceinline__ unsigned omap(float f) {
    const unsigned u = __float_as_uint(f);
    return u ^ (((unsigned)((int)u >> 31)) | 0x80000000u);
}

extern "C" __global__ __launch_bounds__(THREADS, 4)
void knn_kernel(const float* __restrict__ verts, int* __restrict__ out)
{
    // Static LDS 14336 B. Grid 1024 = 4 blocks/CU.
    __shared__ float vdump[NQB][NCH];                   // 8192 B (row per query)
    __shared__ unsigned long long hbk[NQB][CAP];        // 4096 B (packed hit keys)
    __shared__ int cand[NQB][MAXC];                     // 2048 B

    const int t    = threadIdx.x;
    const int lane = t & 63;
    const int wv   = t >> 6;          // wave 0..3
    const int c    = t;               // chunk 0..255 (one per thread)
    const int qbase = blockIdx.x * NQB;

    // Register tile: all 8 block queries per lane. Fast path: folded -2*q
    // coords, qn omitted inside the min (constant per query, re-added once).
    float qx2[QPL], qy2[QPL], qz2[QPL], qn[QPL];
#pragma unroll
    for (int i = 0; i < QPL; ++i) {
        const float x = verts[(qbase + i) * 3 + 0];
        const float y = verts[(qbase + i) * 3 + 1];
        const float z = verts[(qbase + i) * 3 + 2];
        qn[i] = norm3(x, y, z);
        qx2[i] = -2.0f * x; qy2[i] = -2.0f * y; qz2[i] = -2.0f * z;
    }

    // ---------------- PASS 1: per-(chunk,query) MIN, straight from global ---
    // Chunk c's point set: { w*WIN + c*JPW + j : w<4, j<8 }. Per window the
    // chunk is 24 consecutive floats = 6 aligned float4 (96B-aligned base).
    // NO barriers, NO LDS in this phase: waves fully decoupled.
    float mn[QPL];
#pragma unroll
    for (int i = 0; i < QPL; ++i) mn[i] = INFINITY;

    auto pair8 = [&](float px, float py, float pz) {
        const float pw = norm3(px, py, pz);
#pragma unroll
        for (int i = 0; i < QPL; ++i) {
            const float d = __builtin_fmaf(px, qx2[i],
                            __builtin_fmaf(py, qy2[i],
                            __builtin_fmaf(pz, qz2[i], pw)));
            mn[i] = fminf(mn[i], d);
        }
    };

#pragma unroll
    for (int w = 0; w < NWIN; ++w) {
        const float4* vp = (const float4*)(verts + (w * WIN + c * JPW) * 3);
        const float4 A = vp[0], B = vp[1], C = vp[2];
        const float4 D = vp[3], E = vp[4], F = vp[5];
        pair8(A.x, A.y, A.z); pair8(A.w, B.x, B.y);
        pair8(B.z, B.w, C.x); pair8(C.y, C.z, C.w);
        pair8(D.x, D.y, D.z); pair8(D.w, E.x, E.y);
        pair8(E.z, E.w, F.x); pair8(F.y, F.z, F.w);
    }

    // Re-add qn so vdump holds true fast distances (row per query).
#pragma unroll
    for (int i = 0; i < QPL; ++i) {
        mn[i] += qn[i];
        vdump[i][c] = mn[i];
    }
    __syncthreads();
    // -------- From here on, EVERYTHING is wave-local (no barriers/atomics). --
    // Wave wv owns queries {2wv, 2wv+1}.

    // One aligned b128 per lane per query row.
    const float4 sva = *(const float4*)&vdump[wv * 2 + 0][lane * 4];
    const float4 svb = *(const float4*)&vdump[wv * 2 + 1][lane * 4];

    // ---- T' for BOTH queries via fused bitwise binary search (22 bits) -----
    // Two independent dependency chains interleaved for ILP; low 10 bits
    // filled with 1s afterwards (T~ >= exact 20th smallest; proof in journal).
    const unsigned a0 = omap(sva.x), a1 = omap(sva.y);
    const unsigned a2 = omap(sva.z), a3 = omap(sva.w);
    const unsigned b0 = omap(svb.x), b1 = omap(svb.y);
    const unsigned b2 = omap(svb.z), b3 = omap(svb.w);
    unsigned A0 = 0, A1 = 0;
#pragma unroll
    for (int b = 31; b >= 10; --b) {
        const unsigned cv0 = A0 | (1u << b);
        const unsigned cv1 = A1 | (1u << b);
        const int cnt0 = __popcll(__ballot(a0 < cv0)) + __popcll(__ballot(a1 < cv0))
                       + __popcll(__ballot(a2 < cv0)) + __popcll(__ballot(a3 < cv0));
        const int cnt1 = __popcll(__ballot(b0 < cv1)) + __popcll(__ballot(b1 < cv1))
                       + __popcll(__ballot(b2 < cv1)) + __popcll(__ballot(b3 < cv1));
        if (cnt0 <= KK - 1) A0 = cv0;
        if (cnt1 <= KK - 1) A1 = cv1;
    }
    A0 |= 0x3FFu; A1 |= 0x3FFu;
    const float Ts0 = (A0 >> 31) ? __uint_as_float(A0 ^ 0x80000000u)
                                 : __uint_as_float(~A0);
    const float Ts1 = (A1 >> 31) ? __uint_as_float(A1 ^ 0x80000000u)
                                 : __uint_as_float(~A1);
    float Tr[2]; int ncr[2];
    Tr[0] = Ts0 + MARGIN; Tr[1] = Ts1 + MARGIN;

    // ---- Candidate chunks via ballot compaction (no atomics) ---------------
#pragma unroll
    for (int r = 0; r < 2; ++r) {
        const int qq = wv * 2 + r;
        const float4 sv = r ? svb : sva;
        const float T = Tr[r];
        const unsigned long long e0 = __ballot(sv.x <= T);
        const unsigned long long e1 = __ballot(sv.y <= T);
        const unsigned long long e2 = __ballot(sv.z <= T);
        const unsigned long long e3 = __ballot(sv.w <= T);
        const int c0 = __popcll(e0), c1 = __popcll(e1), c2 = __popcll(e2);
        const unsigned long long below = (1ULL << lane) - 1;
        const int k0 = __popcll(e0 & below);
        const int k1 = c0 + __popcll(e1 & below);
        const int k2 = c0 + c1 + __popcll(e2 & below);
        const int k3 = c0 + c1 + c2 + __popcll(e3 & below);
        if ((sv.x <= T) && k0 < MAXC) cand[qq][k0] = lane * 4 + 0;
        if ((sv.y <= T) && k1 < MAXC) cand[qq][k1] = lane * 4 + 1;
        if ((sv.z <= T) && k2 < MAXC) cand[qq][k2] = lane * 4 + 2;
        if ((sv.w <= T) && k3 < MAXC) cand[qq][k3] = lane * 4 + 3;
        ncr[r] = min(c0 + c1 + c2 + __popcll(e3), MAXC);
    }

    // ------- PASS 2 (sparse, fused 2 queries/wave, 6-deep pipeline) ---------
    // Half-wave = one query: lanes 0-31 -> q=2wv, lanes 32-63 -> q=2wv+1.
    // Point p = lane&31 of chunk cc: n = (p>>3)*WIN + cc*JPW + (p&7).
    // Hits stored as packed u64 keys (order-mapped dist << 32 | idx).
    int hc0 = 0, hc1 = 0;                       // per-query hit counts (uniform)
    {
        const int qq = wv * 2 + (lane >> 5);
        const int qg2 = qbase + qq;
        const float qxe = verts[qg2 * 3 + 0];
        const float qye = verts[qg2 * 3 + 1];
        const float qze = verts[qg2 * 3 + 2];
        const float qne = norm3(qxe, qye, qze);
        const float T = (lane < 32) ? Tr[0] : Tr[1];
        const int ncq = (lane < 32) ? ncr[0] : ncr[1];
        const int ncm = max(ncr[0], ncr[1]);
        const int p = lane & 31;
        const int nfix = (p >> 3) * WIN + (p & 7);
        for (int e0 = 0; e0 < ncm; e0 += PD) {  // wave-uniform groups of PD
            float PX[PD], PY[PD], PZ[PD]; int NN[PD];
#pragma unroll
            for (int u = 0; u < PD; ++u) {      // 3*PD independent loads in flight
                const int e = e0 + u;
                const int cc = cand[qq][e < ncq ? e : 0];
                const int n = nfix + cc * JPW;
                NN[u] = n;
                PX[u] = verts[n * 3 + 0];
                PY[u] = verts[n * 3 + 1];
                PZ[u] = verts[n * 3 + 2];
            }
#pragma unroll
            for (int u = 0; u < PD; ++u) {
                const float pw = norm3(PX[u], PY[u], PZ[u]);
                const float d = dist_exact(PX[u], PY[u], PZ[u], pw,
                                           qxe, qye, qze, qne);
                const bool pred = ((e0 + u) < ncq) && (d <= T);
                // Ballot-compacted hit append (no atomics).
                const unsigned long long bal = __ballot(pred);
                const int lc = __popcll(bal & 0xFFFFFFFFULL);
                const int hcv = __popcll(bal >> 32);
                const int base = (lane < 32) ? hc0 : hc1;
                const unsigned long long blw = bal & ((1ULL << lane) - 1);
                const int rank = (lane < 32) ? __popcll(blw)
                                             : __popcll(blw >> 32);
                if (pred) {
                    const int slot = base + rank;
                    if (slot < CAP)
                        hbk[qq][slot] = ((unsigned long long)omap(d) << 32)
                                      | (unsigned)NN[u];
                }
                hc0 += lc; hc1 += hcv;
            }
        }
    }

    // ------- Final: stable top-20 via rank selection (fused both queries) ---
    // rank = #{keys < mine}; unique keys => exact stable ascending (d, idx).
    {
        const int qa = wv * 2, qb = wv * 2 + 1;
        const int kca = min(hc0, CAP), kcb = min(hc1, CAP);
        const unsigned long long keya = (lane < kca) ? hbk[qa][lane] : ~0ULL;
        const unsigned long long keyb = (lane < kcb) ? hbk[qb][lane] : ~0ULL;
        int ranka = 0, rankb = 0;
        const int kcm = max(kca, kcb);
        for (int e = 0; e < kcm; ++e) {         // broadcast LDS reads, pipelined
            if (e < kca) ranka += (hbk[qa][e] < keya) ? 1 : 0;
            if (e < kcb) rankb += (hbk[qb][e] < keyb) ? 1 : 0;
        }
        if (lane < kca && ranka < KK)
            out[(qbase + qa) * KK + ranka] =
                (int)(unsigned)(keya & 0xffffffffULL);
        if (lane < kcb && rankb < KK)
            out[(qbase + qb) * KK + rankb] =
                (int)(unsigned)(keyb & 0xffffffffULL);
    }
}

extern "C" void kernel_launch(void* const* d_in, const int* in_sizes, int n_in,
                              void* d_out, int out_size, void* d_ws, size_t ws_size,
                              hipStream_t stream) {
    // d_in[0] = feats (unused). d_in[1] = vertices [4,8192,3] f32; batch 0 only.
    const float* verts = (const float*)d_in[1];
    int* out = (int*)d_out;
    knn_kernel<<<dim3(NPTS / NQB), dim3(THREADS), 0, stream>>>(verts, out);
}

// Round 22
// 22.717 us; speedup vs baseline: 1.5263x; 1.2074x over previous
//
#include <hip/hip_runtime.h>
#include <math.h>

#define KK 20
#define NPTS 8192
#define NQB 8               // queries per block (= 1 per wave)
#define QPL 8               // queries per lane (pass 1)
#define NCH 512             // half-chunks per query (16 pts: 4 windows x 4)
#define THREADS 512
#define WIN 2048
#define NWIN 4
#define JPW 4               // consecutive points per half-chunk per window
#define CAP 64              // hit buffer capacity per query
#define MAXC 64             // candidate-chunk list capacity per query
#define MARGIN 4e-3f        // >> 2*max|d_fast - d_exact| + 22-bit-T overshoot slack

// Exact (non-contracted) IEEE ops matching the NumPy reference bit-for-bit.
// np.sum (pairwise, n<8) accumulates ascending: (x^2 + y^2) + z^2.
__device__ __forceinline__ float norm3(float x, float y, float z) {
    return __fadd_rn(__fadd_rn(__fmul_rn(x, x), __fmul_rn(y, y)), __fmul_rn(z, z));
}

// np.einsum (optimize=False) remainder falls through DESCENDING for count=3:
// ((z*z') + y*y') + x*x'.  dist = ((-2*dot) + n_src) + n_dst.
__device__ __forceinline__ float dist_exact(float px, float py, float pz, float pw,
                                            float qx, float qy, float qz, float qn) {
    const float dot = __fadd_rn(
        __fadd_rn(__fmul_rn(pz, qz), __fmul_rn(py, qy)), __fmul_rn(px, qx));
    return __fadd_rn(__fadd_rn(__fmul_rn(dot, -2.0f), pw), qn);
}

// Order-preserving float -> u32 map (strictly monotone for all finite floats).
__device__ __forceinline__ unsigned omap(float f) {
    const unsigned u = __float_as_uint(f);
    return u ^ (((unsigned)((int)u >> 31)) | 0x80000000u);
}

extern "C" __global__ __launch_bounds__(THREADS, 8)
void knn_kernel(const float* __restrict__ verts, int* __restrict__ out)
{
    // Static LDS 22528 B. Grid 1024 = 4 blocks/CU x 8 waves = 32 waves/CU.
    __shared__ float vdump[NQB][NCH];                   // 16384 B (SHIFTED minima)
    __shared__ unsigned long long hbk[NQB][CAP];        //  4096 B (packed hit keys)
    __shared__ int cand[NQB][MAXC];                     //  2048 B

    const int t    = threadIdx.x;
    const int lane = t & 63;
    const int wv   = t >> 6;          // wave 0..7 (= its query)
    const int c    = t;               // half-chunk 0..511 (one per thread)
    const int qbase = blockIdx.x * NQB;

    // Register tile: all 8 block queries per lane, folded -2*q coords only
    // (qn is NOT kept: vdump stores shifted minima; shift re-applied later).
    float qx2[QPL], qy2[QPL], qz2[QPL];
#pragma unroll
    for (int i = 0; i < QPL; ++i) {
        qx2[i] = -2.0f * verts[(qbase + i) * 3 + 0];
        qy2[i] = -2.0f * verts[(qbase + i) * 3 + 1];
        qz2[i] = -2.0f * verts[(qbase + i) * 3 + 2];
    }

    // ---------------- PASS 1: per-(half-chunk,query) shifted MIN ------------
    // Half-chunk c = { w*WIN + c*JPW + j : w<4, j<4 }: 12 consecutive floats
    // per window = 3 aligned float4 (48B-aligned base). NO barriers, NO LDS.
    float mn[QPL];
#pragma unroll
    for (int i = 0; i < QPL; ++i) mn[i] = INFINITY;

    auto pair8 = [&](float px, float py, float pz) {
        const float pw = norm3(px, py, pz);
#pragma unroll
        for (int i = 0; i < QPL; ++i) {
            const float d = __builtin_fmaf(px, qx2[i],
                            __builtin_fmaf(py, qy2[i],
                            __builtin_fmaf(pz, qz2[i], pw)));
            mn[i] = fminf(mn[i], d);
        }
    };

#pragma unroll
    for (int w = 0; w < NWIN; ++w) {
        const float4* vp = (const float4*)(verts + (w * WIN + c * JPW) * 3);
        const float4 A = vp[0], B = vp[1], C = vp[2];
        pair8(A.x, A.y, A.z); pair8(A.w, B.x, B.y);
        pair8(B.z, B.w, C.x); pair8(C.y, C.z, C.w);
    }

#pragma unroll
    for (int i = 0; i < QPL; ++i) vdump[i][c] = mn[i];   // shifted (no qn)
    __syncthreads();
    // -------- From here on, EVERYTHING is wave-local (no barriers/atomics). --
    // Wave wv owns query wv. Lane holds shifted minima of chunks {64k+lane}.

    const int qq = wv;
    const int qg2 = qbase + qq;
    const float qxe = verts[qg2 * 3 + 0];
    const float qye = verts[qg2 * 3 + 1];
    const float qze = verts[qg2 * 3 + 2];
    const float qne = norm3(qxe, qye, qze);

    // 8 stride-64 scalar LDS reads: conflict-free (lanes consecutive).
    float sv[8];
#pragma unroll
    for (int k = 0; k < 8; ++k) sv[k] = vdump[qq][k * 64 + lane];

    // ---- T' (shifted) = 20th smallest of 512 half-chunk minima via bitwise
    // binary search on order-mapped u32 (top 22 bits; low 10 filled with 1s —
    // overshoot <= 2^10 ulp, absorbed by MARGIN; only widens the candidate set).
    unsigned uv[8];
#pragma unroll
    for (int k = 0; k < 8; ++k) uv[k] = omap(sv[k]);
    unsigned A = 0;
#pragma unroll
    for (int b = 31; b >= 10; --b) {
        const unsigned cv = A | (1u << b);
        int cnt = 0;
#pragma unroll
        for (int k = 0; k < 8; ++k) cnt += __popcll(__ballot(uv[k] < cv));
        if (cnt <= KK - 1) A = cv;   // max A with count(< A) <= 19
    }
    A |= 0x3FFu;
    const float Tsh = ((A >> 31) ? __uint_as_float(A ^ 0x80000000u)
                                 : __uint_as_float(~A)) + MARGIN;  // shifted T
    const float T = Tsh + qne;                  // true-space T for exact test

    // ---- Candidate half-chunks via ballot compaction (no atomics) ----------
    int nc = 0;
#pragma unroll
    for (int k = 0; k < 8; ++k) {
        const bool pred = (sv[k] <= Tsh);
        const unsigned long long bal = __ballot(pred);
        const int rank = nc + __popcll(bal & ((1ULL << lane) - 1));
        if (pred && rank < MAXC) cand[qq][rank] = k * 64 + lane;
        nc += __popcll(bal);
    }
    nc = min(nc, MAXC);

    // ------- PASS 2 (sparse): 4 cands x 16 pts per wave-step, 16 cands/group -
    // sub = lane>>4 picks candidate; p = lane&15 -> point n = (p>>2)*WIN +
    // cc*JPW + (p&3)  (the half-chunk's true point set). 12 loads in flight.
    int hc = 0;                                 // hit count (wave-uniform)
    {
        const int sub = lane >> 4;
        const int p = lane & 15;
        const int nfix = (p >> 2) * WIN + (p & 3);
        for (int e0 = 0; e0 < nc; e0 += 16) {   // wave-uniform groups of 16
            float PX[4], PY[4], PZ[4]; int NN[4];
#pragma unroll
            for (int u = 0; u < 4; ++u) {       // 12 independent loads in flight
                const int e = e0 + 4 * u + sub;
                const int cc = cand[qq][e < nc ? e : 0];
                const int n = nfix + cc * JPW;
                NN[u] = n;
                PX[u] = verts[n * 3 + 0];
                PY[u] = verts[n * 3 + 1];
                PZ[u] = verts[n * 3 + 2];
            }
#pragma unroll
            for (int u = 0; u < 4; ++u) {
                const float pw = norm3(PX[u], PY[u], PZ[u]);
                const float d = dist_exact(PX[u], PY[u], PZ[u], pw,
                                           qxe, qye, qze, qne);
                const bool pred = ((e0 + 4 * u + sub) < nc) && (d <= T);
                // Ballot-compacted hit append (no atomics).
                const unsigned long long bal = __ballot(pred);
                const int rank = __popcll(bal & ((1ULL << lane) - 1));
                if (pred) {
                    const int slot = hc + rank;
                    if (slot < CAP)
                        hbk[qq][slot] = ((unsigned long long)omap(d) << 32)
                                      | (unsigned)NN[u];
                }
                hc += __popcll(bal);
            }
        }
    }

    // ------- Final: stable top-20 via rank selection (no sort chain) --------
    // rank = #{keys < mine}; unique keys => exact stable ascending (d, idx).
    {
        const int kc = min(hc, CAP);            // kc >= 20 guaranteed
        const unsigned long long mykey = (lane < kc) ? hbk[qq][lane] : ~0ULL;
        int rank = 0;
        for (int e = 0; e < kc; ++e)            // broadcast LDS reads, pipelined
            rank += (hbk[qq][e] < mykey) ? 1 : 0;
        if (lane < kc && rank < KK)
            out[(qbase + qq) * KK + rank] =
                (int)(unsigned)(mykey & 0xffffffffULL);
    }
}

extern "C" void kernel_launch(void* const* d_in, const int* in_sizes, int n_in,
                              void* d_out, int out_size, void* d_ws, size_t ws_size,
                              hipStream_t stream) {
    // d_in[0] = feats (unused). d_in[1] = vertices [4,8192,3] f32; batch 0 only.
    const float* verts = (const float*)d_in[1];
    int* out = (int*)d_out;
    knn_kernel<<<dim3(NPTS / NQB), dim3(THREADS), 0, stream>>>(verts, out);
}